// Round 5
// baseline (258.580 us; speedup 1.0000x reference)
//
#include <hip/hip_runtime.h>
#include <hip/hip_bf16.h>

// ---------------- problem constants ----------------
constexpr int E_ = 16, K_ = 2, D_ = 1024, F_ = 512, T_ = 4096;
constexpr int TK_ = T_ * K_;          // 8192 (token,expert) slots
constexpr int CAP_ = 2048;            // per-expert capacity
constexpr int BM_ = 128;              // row-region alignment (offsets)
constexpr int ROWS_MAX = 10240;       // TK + E*(BM-1) rounded up

// ---------------- workspace layout (bytes) ----------------
// No transposed-weight buffers anymore: gemms read f32 weights directly and
// cast+transpose during LDS staging. Ye (f32) aliases Xg (dead after gemm1).
constexpr size_t OFF_H    = 0;                           // bf16 [ROWS_MAX][F]
constexpr size_t SZ_H     = (size_t)ROWS_MAX * F_ * 2;
constexpr size_t OFF_XG   = OFF_H + SZ_H;                // bf16 [ROWS_MAX][D]
constexpr size_t OFF_YE   = OFF_XG;                      // f32 [ROWS_MAX][D], 40 MB
constexpr size_t SZ_YE    = (size_t)ROWS_MAX * D_ * 4;
constexpr size_t OFF_META = OFF_XG + SZ_YE;
// meta: cnt_c[16], off_al[16], row_token[ROWS_MAX], row_weight[ROWS_MAX], slot_row[TK]

typedef __attribute__((ext_vector_type(8))) short short8;
typedef __attribute__((ext_vector_type(4))) float float4v;

__device__ __forceinline__ unsigned short f2bf(float f) {
  union { float f; unsigned int u; } v; v.f = f;
  unsigned int r = (v.u + 0x7fffu + ((v.u >> 16) & 1u)) >> 16;
  return (unsigned short)r;
}

// packed f32->bf16 RNE (1 instr per pair); low half = src0
__device__ __forceinline__ unsigned int cvt2(float lo, float hi) {
  unsigned int r;
  asm("v_cvt_pk_bf16_f32 %0, %1, %2" : "=v"(r) : "v"(lo), "v"(hi));
  return r;
}

__device__ __forceinline__ void load_lds16(const unsigned short* g, unsigned short* l) {
  __builtin_amdgcn_global_load_lds(
      (const __attribute__((address_space(1))) unsigned int*)g,
      (__attribute__((address_space(3))) unsigned int*)l,
      16, 0, 0);
}

// raw barrier without the compiler's vmcnt(0) drain; memory-clobber asms pin
// all memory ops (stage intrinsics, ds ops) on their side of the barrier.
__device__ __forceinline__ void barrier_nodrain() {
  asm volatile("" ::: "memory");
  __builtin_amdgcn_s_barrier();
  asm volatile("" ::: "memory");
}

// ---------------- dispatch: one block per expert, redundant histogram ----------
__launch_bounds__(256)
__global__ void dispatch_k(const int* __restrict__ idx, const float* __restrict__ tw,
                           int* __restrict__ cnt_c, int* __restrict__ off_al,
                           int* __restrict__ row_token, float* __restrict__ row_weight,
                           int* __restrict__ slot_row) {
  __shared__ int hist[E_];
  __shared__ int off_s, pad_s, cnt_s;
  int e = blockIdx.x, tid = threadIdx.x;
  if (tid < E_) hist[tid] = 0;
  if (tid == 0) cnt_s = 0;
  __syncthreads();
  for (int i = tid; i < TK_; i += 256) atomicAdd(&hist[idx[i]], 1);
  __syncthreads();
  if (tid == 0) {
    int run = 0, off = 0, myc = 0;
    for (int ee = 0; ee < E_; ++ee) {
      int c = hist[ee] > CAP_ ? CAP_ : hist[ee];
      if (ee == e) { off = run; myc = c; }
      run += (c + BM_ - 1) & ~(BM_ - 1);
    }
    off_s = off; pad_s = (myc + BM_ - 1) & ~(BM_ - 1);
    cnt_c[e] = myc; off_al[e] = off;
  }
  __syncthreads();
  int off = off_s, pad = pad_s;
  for (int r = tid; r < pad; r += 256) row_token[off + r] = -1;
  __syncthreads();
  for (int i = tid; i < TK_; i += 256) {
    if (idx[i] == e) {
      int r = atomicAdd(&cnt_s, 1);
      int row = -1;
      if (r < CAP_) {
        row = off + r;
        row_token[row] = i >> 1;              // source token
        row_weight[row] = tw[i];
      }
      slot_row[i] = row;
    }
  }
}

// ---------------- gather tokens -> bf16 grouped rows ----------------
__global__ void gather_k(const float* __restrict__ hidden, const int* __restrict__ row_token,
                         unsigned short* __restrict__ Xg) {
  int r = blockIdx.x;
  int tok = row_token[r];
  int c = threadIdx.x * 4;
  ushort4 o;
  if ((unsigned)tok < (unsigned)T_) {          // tail region is uninitialized
    float4 v = *(const float4*)(hidden + (size_t)tok * D_ + c);
    o.x = f2bf(v.x); o.y = f2bf(v.y); o.z = f2bf(v.z); o.w = f2bf(v.w);
  } else {
    o.x = 0; o.y = 0; o.z = 0; o.w = 0;
  }
  *(ushort4*)(Xg + (size_t)r * D_ + c) = o;
}

// Staging scheme (both gemms):
//  A (bf16, grouped rows): global_load_lds into XOR-swizzled [row][k] LDS,
//    double-buffered. Slot sl of row holds col8 = sl ^ (row&7).
//  B (f32 weights [k][n]-major): each thread loads 8 K-STRIDED f32 (a column
//    chunk at fixed n; per-j the wave reads 256B contiguous), cvt_pk to bf16x8,
//    ONE ds_write_b128 into the same XOR layout at row n. Regs->LDS->compute
//    within one barrier pair => single B buffer.
//  Sync (T3+T4): per K-step issue 32 B-dwords + 2 A-gload_lds for step t+1,
//    then s_waitcnt vmcnt(34) (waits only step t's A-stage; the 34 new ops
//    stay in flight across the barrier). lgkmcnt(0) makes ds_writes visible.

// ---------------- GEMM1: H = silu(Xg@Wg) * (Xg@Wu), 64x64 tile ----------------
__launch_bounds__(256, 4)
__global__ void gemm1_k(const unsigned short* __restrict__ Xg,
                        const float* __restrict__ Wg, const float* __restrict__ Wu,
                        unsigned short* __restrict__ Hbuf,
                        const int* __restrict__ cnt_c, const int* __restrict__ off_al) {
  int bid = blockIdx.x;
  int swz = (bid & 7) * 512 + (bid >> 3);     // 4096 blocks, 512/XCD chunk
  int e = swz >> 8, mt = (swz >> 3) & 31, nt = swz & 7;
  int cnt = cnt_c[e];
  if (mt * 64 >= cnt) return;
  int rbase = off_al[e] + mt * 64;

  __shared__ unsigned short lA[2][64 * 64];
  __shared__ unsigned short lBg[64 * 64];
  __shared__ unsigned short lBu[64 * 64];

  int tid = threadIdx.x, wid = tid >> 6, lane = tid & 63;
  int wm = wid >> 1, wn = wid & 1;
  int quad = lane >> 4, l15 = lane & 15;
  int sw = l15 & 7;

  const unsigned short* gA = Xg + (size_t)rbase * D_;
  // weight bases: +nt*64 (n panel) +lane (this thread's n); index adds k*F_.
  const float* gW0 = Wg + (size_t)e * D_ * F_ + nt * 64 + lane;
  const float* gW1 = Wu + (size_t)e * D_ * F_ + nt * 64 + lane;

  float4v accg[2][2], accu[2][2];
#pragma unroll
  for (int i = 0; i < 2; ++i)
#pragma unroll
    for (int j = 0; j < 2; ++j) {
      accg[i][j] = (float4v){0.f, 0.f, 0.f, 0.f};
      accu[i][j] = (float4v){0.f, 0.f, 0.f, 0.f};
    }

  float bga[8], bgb[8], bua[8], bub[8];       // chunk a: k8=wid, chunk b: k8=wid+4
  auto loadB = [&](int k0) {                  // 32 global_load_dword
#pragma unroll
    for (int j = 0; j < 8; ++j) {
      size_t ra = (size_t)(k0 + wid * 8 + j) * F_;
      size_t rb = (size_t)(k0 + (wid + 4) * 8 + j) * F_;
      bga[j] = gW0[ra]; bgb[j] = gW0[rb];
      bua[j] = gW1[ra]; bub[j] = gW1[rb];
    }
  };
  int sA = (wid ^ (lane & 7)) * 8, sB = ((wid + 4) ^ (lane & 7)) * 8;
  int wb = lane * 64;
  auto writeB = [&]() {                       // 4 ds_write_b128
    uint4 p;
    p.x = cvt2(bga[0], bga[1]); p.y = cvt2(bga[2], bga[3]);
    p.z = cvt2(bga[4], bga[5]); p.w = cvt2(bga[6], bga[7]);
    *(uint4*)&lBg[wb + sA] = p;
    p.x = cvt2(bgb[0], bgb[1]); p.y = cvt2(bgb[2], bgb[3]);
    p.z = cvt2(bgb[4], bgb[5]); p.w = cvt2(bgb[6], bgb[7]);
    *(uint4*)&lBg[wb + sB] = p;
    p.x = cvt2(bua[0], bua[1]); p.y = cvt2(bua[2], bua[3]);
    p.z = cvt2(bua[4], bua[5]); p.w = cvt2(bua[6], bua[7]);
    *(uint4*)&lBu[wb + sA] = p;
    p.x = cvt2(bub[0], bub[1]); p.y = cvt2(bub[2], bub[3]);
    p.z = cvt2(bub[4], bub[5]); p.w = cvt2(bub[6], bub[7]);
    *(uint4*)&lBu[wb + sB] = p;
  };
  auto stageA = [&](int buf, int k0) {        // 2 global_load_lds
#pragma unroll
    for (int it = 0; it < 2; ++it) {
      int fw = it * 256 + wid * 64;
      int f = fw + lane;
      int row = f >> 3, c8 = (f & 7) ^ (row & 7);
      load_lds16(gA + (size_t)row * D_ + k0 + c8 * 8, &lA[buf][fw * 8]);
    }
  };

  loadB(0);
  stageA(0, 0);

  for (int kt = 0; kt < 16; ++kt) {
    int cur = kt & 1;
    writeB();                                  // compiler waits this step's B regs
    if (kt + 1 < 16) {
      loadB((kt + 1) * 64);
      stageA(cur ^ 1, (kt + 1) * 64);
      asm volatile("s_waitcnt vmcnt(34)" ::: "memory");  // this step's A landed
    } else {
      asm volatile("s_waitcnt vmcnt(0)" ::: "memory");
    }
    asm volatile("s_waitcnt lgkmcnt(0)" ::: "memory");   // ds_writes visible
    __builtin_amdgcn_sched_barrier(0);
    barrier_nodrain();
#pragma unroll
    for (int kc = 0; kc < 2; ++kc) {
      short8 af[2], bg[2], bu[2];
#pragma unroll
      for (int i = 0; i < 2; ++i) {
        int r = wm * 32 + i * 16 + l15;
        af[i] = *(const short8*)&lA[cur][r * 64 + ((kc * 4 + quad) ^ sw) * 8];
      }
#pragma unroll
      for (int j = 0; j < 2; ++j) {
        int n = wn * 32 + j * 16 + l15;
        bg[j] = *(const short8*)&lBg[n * 64 + ((kc * 4 + quad) ^ sw) * 8];
        bu[j] = *(const short8*)&lBu[n * 64 + ((kc * 4 + quad) ^ sw) * 8];
      }
#pragma unroll
      for (int i = 0; i < 2; ++i)
#pragma unroll
        for (int j = 0; j < 2; ++j) {
          accg[i][j] = __builtin_amdgcn_mfma_f32_16x16x32_bf16(af[i], bg[j], accg[i][j], 0, 0, 0);
          accu[i][j] = __builtin_amdgcn_mfma_f32_16x16x32_bf16(af[i], bu[j], accu[i][j], 0, 0, 0);
        }
    }
    barrier_nodrain();                         // LDS free for next step's writes
  }

  int rem = cnt - mt * 64;
#pragma unroll
  for (int i = 0; i < 2; ++i)
#pragma unroll
    for (int j = 0; j < 2; ++j)
#pragma unroll
      for (int r = 0; r < 4; ++r) {
        int row = wm * 32 + i * 16 + quad * 4 + r;
        if (row < rem) {
          float g = accg[i][j][r], u = accu[i][j][r];
          float h = (g / (1.f + __expf(-g))) * u;
          int n = nt * 64 + wn * 32 + j * 16 + l15;
          Hbuf[(size_t)(rbase + row) * F_ + n] = f2bf(h);
        }
      }
}

// ---------------- GEMM2: Ye = H @ w_down, 64x128 tile, f32 stores ----------
__launch_bounds__(256, 4)
__global__ void gemm2_k(const unsigned short* __restrict__ Hbuf,
                        const float* __restrict__ Wd,
                        float* __restrict__ Ye,
                        const int* __restrict__ cnt_c, const int* __restrict__ off_al) {
  int bid = blockIdx.x;
  int swz = (bid & 7) * 512 + (bid >> 3);
  int e = swz >> 8, mt = (swz >> 3) & 31, nt = swz & 7;
  int cnt = cnt_c[e];
  if (mt * 64 >= cnt) return;
  int rbase = off_al[e] + mt * 64;

  __shared__ unsigned short lA[2][64 * 64];
  __shared__ unsigned short lB[128 * 64];

  int tid = threadIdx.x, wid = tid >> 6, lane = tid & 63;
  int wm = wid >> 1, wn = wid & 1;
  int quad = lane >> 4, l15 = lane & 15;
  int sw = l15 & 7;

  const unsigned short* gA = Hbuf + (size_t)rbase * F_;
  const float* gW = Wd + (size_t)e * F_ * D_ + nt * 128 + lane;   // [k=F][n=D]

  float4v acc[2][4];
#pragma unroll
  for (int i = 0; i < 2; ++i)
#pragma unroll
    for (int j = 0; j < 4; ++j) acc[i][j] = (float4v){0.f, 0.f, 0.f, 0.f};

  float b[4][8];   // chunk c: n = (c&1)*64 + lane, k8 = wid + (c>>1)*4
  auto loadB = [&](int k0) {                  // 32 global_load_dword
#pragma unroll
    for (int c = 0; c < 4; ++c)
#pragma unroll
      for (int j = 0; j < 8; ++j)
        b[c][j] = gW[(size_t)(k0 + (wid + (c >> 1) * 4) * 8 + j) * D_ + (c & 1) * 64];
  };
  auto writeB = [&]() {                       // 4 ds_write_b128
#pragma unroll
    for (int c = 0; c < 4; ++c) {
      int n = (c & 1) * 64 + lane;
      int s = ((wid + (c >> 1) * 4) ^ (lane & 7)) * 8;   // n&7 == lane&7
      uint4 p;
      p.x = cvt2(b[c][0], b[c][1]); p.y = cvt2(b[c][2], b[c][3]);
      p.z = cvt2(b[c][4], b[c][5]); p.w = cvt2(b[c][6], b[c][7]);
      *(uint4*)&lB[n * 64 + s] = p;
    }
  };
  auto stageA = [&](int buf, int k0) {        // 2 global_load_lds
#pragma unroll
    for (int it = 0; it < 2; ++it) {
      int fw = it * 256 + wid * 64;
      int f = fw + lane;
      int row = f >> 3, c8 = (f & 7) ^ (row & 7);
      load_lds16(gA + (size_t)row * F_ + k0 + c8 * 8, &lA[buf][fw * 8]);
    }
  };

  loadB(0);
  stageA(0, 0);

  for (int kt = 0; kt < 8; ++kt) {
    int cur = kt & 1;
    writeB();
    if (kt + 1 < 8) {
      loadB((kt + 1) * 64);
      stageA(cur ^ 1, (kt + 1) * 64);
      asm volatile("s_waitcnt vmcnt(34)" ::: "memory");
    } else {
      asm volatile("s_waitcnt vmcnt(0)" ::: "memory");
    }
    asm volatile("s_waitcnt lgkmcnt(0)" ::: "memory");
    __builtin_amdgcn_sched_barrier(0);
    barrier_nodrain();
#pragma unroll
    for (int kc = 0; kc < 2; ++kc) {
      short8 af[2], bf[4];
#pragma unroll
      for (int i = 0; i < 2; ++i) {
        int r = wm * 32 + i * 16 + l15;
        af[i] = *(const short8*)&lA[cur][r * 64 + ((kc * 4 + quad) ^ sw) * 8];
      }
#pragma unroll
      for (int j = 0; j < 4; ++j) {
        int n = wn * 64 + j * 16 + l15;
        bf[j] = *(const short8*)&lB[n * 64 + ((kc * 4 + quad) ^ sw) * 8];
      }
#pragma unroll
      for (int i = 0; i < 2; ++i)
#pragma unroll
        for (int j = 0; j < 4; ++j)
          acc[i][j] = __builtin_amdgcn_mfma_f32_16x16x32_bf16(af[i], bf[j], acc[i][j], 0, 0, 0);
    }
    barrier_nodrain();
  }

  int rem = cnt - mt * 64;
#pragma unroll
  for (int i = 0; i < 2; ++i)
#pragma unroll
    for (int r = 0; r < 4; ++r) {
      int row = wm * 32 + i * 16 + quad * 4 + r;
      if (row < rem) {
        float* yp = Ye + (size_t)(rbase + row) * D_ + nt * 128 + wn * 64 + l15;
#pragma unroll
        for (int j = 0; j < 4; ++j) yp[j * 16] = acc[i][j][r];
      }
    }
}

// ---------------- combine: out[t] = w0*Ye[r0] + w1*Ye[r1] --------------------
__global__ void combine_k(const float* __restrict__ Ye, const int* __restrict__ slot_row,
                          const float* __restrict__ row_weight, float* __restrict__ out) {
  int t = blockIdx.x;
  int c = threadIdx.x * 4;
  int r0 = slot_row[2 * t], r1 = slot_row[2 * t + 1];
  float4 acc = {0.f, 0.f, 0.f, 0.f};
  if (r0 >= 0) {
    float w = row_weight[r0];
    float4 y = *(const float4*)(Ye + (size_t)r0 * D_ + c);
    acc.x = w * y.x; acc.y = w * y.y; acc.z = w * y.z; acc.w = w * y.w;
  }
  if (r1 >= 0) {
    float w = row_weight[r1];
    float4 y = *(const float4*)(Ye + (size_t)r1 * D_ + c);
    acc.x += w * y.x; acc.y += w * y.y; acc.z += w * y.z; acc.w += w * y.w;
  }
  *(float4*)(out + (size_t)t * D_ + c) = acc;
}

// ---------------- launch ----------------
extern "C" void kernel_launch(void* const* d_in, const int* in_sizes, int n_in,
                              void* d_out, int out_size, void* d_ws, size_t ws_size,
                              hipStream_t stream) {
  const float* hidden  = (const float*)d_in[0];
  const int*   topkidx = (const int*)d_in[1];
  const float* topkw   = (const float*)d_in[2];
  const float* w_gate  = (const float*)d_in[3];
  const float* w_up    = (const float*)d_in[4];
  const float* w_down  = (const float*)d_in[5];
  float* out = (float*)d_out;

  char* ws = (char*)d_ws;
  unsigned short* Hb  = (unsigned short*)(ws + OFF_H);
  unsigned short* Xg  = (unsigned short*)(ws + OFF_XG);
  float* Ye           = (float*)(ws + OFF_YE);   // aliases Xg (dead after gemm1)
  int* meta           = (int*)(ws + OFF_META);
  int* cnt_c     = meta;
  int* off_al    = meta + 16;
  int* row_token = meta + 32;
  float* row_weight = (float*)(meta + 32 + ROWS_MAX);
  int* slot_row  = meta + 32 + 2 * ROWS_MAX;

  dispatch_k<<<E_, 256, 0, stream>>>(topkidx, topkw, cnt_c, off_al, row_token, row_weight,
                                     slot_row);
  gather_k<<<ROWS_MAX, 256, 0, stream>>>(hidden, row_token, Xg);

  gemm1_k<<<4096, 256, 0, stream>>>(Xg, w_gate, w_up, Hb, cnt_c, off_al);
  gemm2_k<<<4096, 256, 0, stream>>>(Hb, w_down, Ye, cnt_c, off_al);
  combine_k<<<T_, 256, 0, stream>>>(Ye, slot_row, row_weight, out);
}

// Round 6
// 238.769 us; speedup vs baseline: 1.0830x; 1.0830x over previous
//
#include <hip/hip_runtime.h>
#include <hip/hip_bf16.h>

// ---------------- problem constants ----------------
constexpr int E_ = 16, K_ = 2, D_ = 1024, F_ = 512, T_ = 4096;
constexpr int TK_ = T_ * K_;          // 8192 (token,expert) slots
constexpr int CAP_ = 2048;            // per-expert capacity
constexpr int BM_ = 128;              // row-region alignment (offsets)
constexpr int ROWS_MAX = 10240;       // TK + E*(BM-1) rounded up

// ---------------- workspace layout (bytes) ----------------
// WdT first (live through gemm2); WgT/WuT/Xg are dead after gemm1, so the f32
// Ye buffer (42 MB) aliases them (starts at OFF_WGT, ends < OFF_H).
constexpr size_t SZ_W   = (size_t)E_ * F_ * D_ * 2;      // one bf16 weight matrix
constexpr size_t OFF_WDT  = 0;
constexpr size_t OFF_WGT  = OFF_WDT + SZ_W;
constexpr size_t OFF_WUT  = OFF_WGT + SZ_W;
constexpr size_t OFF_XG   = OFF_WUT + SZ_W;
constexpr size_t SZ_XG  = (size_t)ROWS_MAX * D_ * 2;
constexpr size_t OFF_H    = OFF_XG + SZ_XG;
constexpr size_t SZ_H   = (size_t)ROWS_MAX * F_ * 2;
constexpr size_t OFF_META = OFF_H + SZ_H;
constexpr size_t OFF_YE   = OFF_WGT;                     // f32 [ROWS_MAX][D], 42 MB
static_assert(OFF_YE + (size_t)ROWS_MAX * D_ * 4 <= OFF_H, "Ye overlaps live buffers");
// meta: cnt_c[16], off_al[16], row_token[ROWS_MAX], row_weight[ROWS_MAX], slot_row[TK]

typedef __attribute__((ext_vector_type(8))) short short8;
typedef __attribute__((ext_vector_type(4))) float float4v;

__device__ __forceinline__ unsigned short f2bf(float f) {
  union { float f; unsigned int u; } v; v.f = f;
  unsigned int r = (v.u + 0x7fffu + ((v.u >> 16) & 1u)) >> 16;
  return (unsigned short)r;
}

__device__ __forceinline__ void load_lds16(const unsigned short* g, unsigned short* l) {
  __builtin_amdgcn_global_load_lds(
      (const __attribute__((address_space(1))) unsigned int*)g,
      (__attribute__((address_space(3))) unsigned int*)l,
      16, 0, 0);
}

// raw barrier without the compiler's vmcnt(0) drain; memory-clobber asms pin
// all memory ops (stage intrinsics, ds_reads) on their side of the barrier.
__device__ __forceinline__ void barrier_nodrain() {
  asm volatile("" ::: "memory");
  __builtin_amdgcn_s_barrier();
  asm volatile("" ::: "memory");
}

// ---------------- prep: dispatch (16 blocks) + weight transpose (6144 blocks) ---
// Fused because they are independent and the stream serializes kernels:
// dispatch's ~10 us hides entirely under the transpose.
//
// dispatch part (blocks 0..15, one per expert): redundant 16-bin histogram,
// derive own offset, init own padded region, rank-assign own expert's slots.
// transpose part (blocks 16..6159): 64x64 f32 tile -> bf16 [C][R].
//   Phase-1: 4x float4/thread -> LDS [64][65] (2-way free banks). Phase-2:
//   c=(it*4+w)*8+(l>>3), r8=(l&7)*8 -> reads tile[r8+j][c] (2-way free banks);
//   16B short8 store, 128B row segments.
__launch_bounds__(256)
__global__ void prep_k(const int* __restrict__ idx, const float* __restrict__ tw,
                       const float* __restrict__ wg, const float* __restrict__ wu,
                       const float* __restrict__ wd,
                       unsigned short* __restrict__ WgT, unsigned short* __restrict__ WuT,
                       unsigned short* __restrict__ WdT,
                       int* __restrict__ cnt_c, int* __restrict__ off_al,
                       int* __restrict__ row_token, float* __restrict__ row_weight,
                       int* __restrict__ slot_row) {
  __shared__ float tile[64][65];
  __shared__ int hist[E_];
  __shared__ int off_s, pad_s, cnt_s;
  int bid = blockIdx.x, tid = threadIdx.x;

  if (bid < E_) {
    // ---- dispatch path ----
    int e = bid;
    if (tid < E_) hist[tid] = 0;
    if (tid == 0) cnt_s = 0;
    __syncthreads();
    for (int i = tid; i < TK_; i += 256) atomicAdd(&hist[idx[i]], 1);
    __syncthreads();
    if (tid == 0) {
      int run = 0, off = 0, myc = 0;
      for (int ee = 0; ee < E_; ++ee) {
        int c = hist[ee] > CAP_ ? CAP_ : hist[ee];
        if (ee == e) { off = run; myc = c; }
        run += (c + BM_ - 1) & ~(BM_ - 1);
      }
      off_s = off; pad_s = (myc + BM_ - 1) & ~(BM_ - 1);
      cnt_c[e] = myc; off_al[e] = off;
    }
    __syncthreads();
    int off = off_s, pad = pad_s;
    for (int r = tid; r < pad; r += 256) row_token[off + r] = -1;
    __syncthreads();
    for (int i = tid; i < TK_; i += 256) {
      if (idx[i] == e) {
        int r = atomicAdd(&cnt_s, 1);
        int row = -1;
        if (r < CAP_) {
          row = off + r;
          row_token[row] = i >> 1;              // source token
          row_weight[row] = tw[i];
        }
        slot_row[i] = row;
      }
    }
    return;
  }

  // ---- transpose path ----
  int g = bid - E_;                   // 0..6143
  int z = g >> 7, t = g & 127;        // z: 0..47, t: 0..127
  int kind = z >> 4, e = z & 15;
  int R = (kind == 2) ? F_ : D_;
  int C = (kind == 2) ? D_ : F_;
  const float* s = ((kind == 0) ? wg : (kind == 1) ? wu : wd) + (size_t)e * R * C;
  unsigned short* d = ((kind == 0) ? WgT : (kind == 1) ? WuT : WdT) + (size_t)e * R * C;
  int tilesX = C >> 6;                // C/64
  int r0 = (t / tilesX) * 64, c0 = (t % tilesX) * 64;

  int lr = tid >> 4;                  // 0..15
  int lc = (tid & 15) * 4;            // 0..60
#pragma unroll
  for (int it = 0; it < 4; ++it) {
    int row = lr + it * 16;
    float4 v = *(const float4*)(s + (size_t)(r0 + row) * C + (c0 + lc));
    tile[row][lc + 0] = v.x; tile[row][lc + 1] = v.y;
    tile[row][lc + 2] = v.z; tile[row][lc + 3] = v.w;
  }
  __syncthreads();

  int w = tid >> 6, l = tid & 63;
#pragma unroll
  for (int it = 0; it < 2; ++it) {
    int c = (it * 4 + w) * 8 + (l >> 3);
    int r8 = (l & 7) * 8;
    short8 o;
#pragma unroll
    for (int j = 0; j < 8; ++j) o[j] = (short)f2bf(tile[r8 + j][c]);
    *(short8*)(d + (size_t)(c0 + c) * R + (r0 + r8)) = o;
  }
}

// ---------------- gather tokens -> bf16 grouped rows ----------------
__global__ void gather_k(const float* __restrict__ hidden, const int* __restrict__ row_token,
                         unsigned short* __restrict__ Xg) {
  int r = blockIdx.x;
  int tok = row_token[r];
  int c = threadIdx.x * 4;
  ushort4 o;
  if ((unsigned)tok < (unsigned)T_) {          // clamp: tail region is uninitialized
    float4 v = *(const float4*)(hidden + (size_t)tok * D_ + c);
    o.x = f2bf(v.x); o.y = f2bf(v.y); o.z = f2bf(v.z); o.w = f2bf(v.w);
  } else {
    o.x = 0; o.y = 0; o.z = 0; o.w = 0;
  }
  *(ushort4*)(Xg + (size_t)r * D_ + c) = o;
}

// Swizzled LDS staging (unchanged scheme): LDS slot sl of row holds global col8
// sl ^ (row&7); fragment reads use slot (c ^ (row&7)). Bank-conflict-free.
//
// K-loop sync (T3+T4): per step, issue next stage's 6 global_load_lds, then
// s_waitcnt vmcnt(6) (waits ONLY the previous stage's 6; new 6 stay in flight
// across the barrier), raw s_barrier, compute, raw s_barrier (frees cur buf
// for the next iteration's stage). No vmcnt(0) drain in the main loop.

// ---------------- GEMM1: H = silu(Xg@Wg) * (Xg@Wu), 64x64 tile ----------------
__launch_bounds__(256)
__global__ void gemm1_k(const unsigned short* __restrict__ Xg,
                        const unsigned short* __restrict__ WgT,
                        const unsigned short* __restrict__ WuT,
                        unsigned short* __restrict__ Hbuf,
                        const int* __restrict__ cnt_c, const int* __restrict__ off_al) {
  int bid = blockIdx.x;
  int swz = (bid & 7) * 512 + (bid >> 3);     // 4096 blocks, 512/XCD chunk
  int e = swz >> 8, mt = (swz >> 3) & 31, nt = swz & 7;
  int cnt = cnt_c[e];
  if (mt * 64 >= cnt) return;
  int rbase = off_al[e] + mt * 64;

  __shared__ unsigned short lA[2][64 * 64];
  __shared__ unsigned short lBg[2][64 * 64];
  __shared__ unsigned short lBu[2][64 * 64];

  int tid = threadIdx.x, wid = tid >> 6, lane = tid & 63;
  int wm = wid >> 1, wn = wid & 1;
  int quad = lane >> 4, l15 = lane & 15;
  int sw = l15 & 7;

  const unsigned short* gA = Xg + (size_t)rbase * D_;
  const unsigned short* gB0 = WgT + ((size_t)e * F_ + nt * 64) * D_;
  const unsigned short* gB1 = WuT + ((size_t)e * F_ + nt * 64) * D_;

  float4v accg[2][2], accu[2][2];
#pragma unroll
  for (int i = 0; i < 2; ++i)
#pragma unroll
    for (int j = 0; j < 2; ++j) {
      accg[i][j] = (float4v){0.f, 0.f, 0.f, 0.f};
      accu[i][j] = (float4v){0.f, 0.f, 0.f, 0.f};
    }

  auto stage = [&](int buf, int k0) {         // 6 global_load_lds / thread
#pragma unroll
    for (int it = 0; it < 2; ++it) {
      int fw = it * 256 + wid * 64;
      int f = fw + lane;
      int row = f >> 3, c8 = (f & 7) ^ (row & 7);
      size_t go = (size_t)row * D_ + k0 + c8 * 8;
      load_lds16(gA + go, &lA[buf][fw * 8]);
      load_lds16(gB0 + go, &lBg[buf][fw * 8]);
      load_lds16(gB1 + go, &lBu[buf][fw * 8]);
    }
  };

  stage(0, 0);

  for (int kt = 0; kt < 16; ++kt) {
    int cur = kt & 1;
    if (kt + 1 < 16) {
      stage(cur ^ 1, (kt + 1) * 64);
      asm volatile("s_waitcnt vmcnt(6)" ::: "memory");   // prev stage complete
    } else {
      asm volatile("s_waitcnt vmcnt(0)" ::: "memory");
    }
    __builtin_amdgcn_sched_barrier(0);
    barrier_nodrain();                         // everyone's prev stage complete
#pragma unroll
    for (int kc = 0; kc < 2; ++kc) {
      short8 af[2], bg[2], bu[2];
#pragma unroll
      for (int i = 0; i < 2; ++i) {
        int r = wm * 32 + i * 16 + l15;
        af[i] = *(const short8*)&lA[cur][r * 64 + ((kc * 4 + quad) ^ sw) * 8];
      }
#pragma unroll
      for (int j = 0; j < 2; ++j) {
        int n = wn * 32 + j * 16 + l15;
        bg[j] = *(const short8*)&lBg[cur][n * 64 + ((kc * 4 + quad) ^ sw) * 8];
        bu[j] = *(const short8*)&lBu[cur][n * 64 + ((kc * 4 + quad) ^ sw) * 8];
      }
#pragma unroll
      for (int i = 0; i < 2; ++i)
#pragma unroll
        for (int j = 0; j < 2; ++j) {
          accg[i][j] = __builtin_amdgcn_mfma_f32_16x16x32_bf16(af[i], bg[j], accg[i][j], 0, 0, 0);
          accu[i][j] = __builtin_amdgcn_mfma_f32_16x16x32_bf16(af[i], bu[j], accu[i][j], 0, 0, 0);
        }
    }
    barrier_nodrain();                         // cur buf free for overwrite
  }

  int rem = cnt - mt * 64;
#pragma unroll
  for (int i = 0; i < 2; ++i)
#pragma unroll
    for (int j = 0; j < 2; ++j)
#pragma unroll
      for (int r = 0; r < 4; ++r) {
        int row = wm * 32 + i * 16 + quad * 4 + r;
        if (row < rem) {
          float g = accg[i][j][r], u = accu[i][j][r];
          float h = (g / (1.f + __expf(-g))) * u;
          int n = nt * 64 + wn * 32 + j * 16 + l15;
          Hbuf[(size_t)(rbase + row) * F_ + n] = f2bf(h);
        }
      }
}

// ---------------- GEMM2: Ye = H @ WdT^T, plain f32 stores (no atomics) ----------
__launch_bounds__(256)
__global__ void gemm2_k(const unsigned short* __restrict__ Hbuf,
                        const unsigned short* __restrict__ WdT,
                        float* __restrict__ Ye,
                        const int* __restrict__ cnt_c, const int* __restrict__ off_al) {
  int bid = blockIdx.x;
  int swz = (bid & 7) * 512 + (bid >> 3);
  int e = swz >> 8, mt = (swz >> 3) & 31, nt = swz & 7;
  int cnt = cnt_c[e];
  if (mt * 64 >= cnt) return;
  int rbase = off_al[e] + mt * 64;

  __shared__ unsigned short lA[2][64 * 64];
  __shared__ unsigned short lB[2][128 * 64];

  int tid = threadIdx.x, wid = tid >> 6, lane = tid & 63;
  int wm = wid >> 1, wn = wid & 1;
  int quad = lane >> 4, l15 = lane & 15;
  int sw = l15 & 7;

  const unsigned short* gA = Hbuf + (size_t)rbase * F_;
  const unsigned short* gB = WdT + ((size_t)e * D_ + nt * 128) * F_;

  float4v acc[2][4];
#pragma unroll
  for (int i = 0; i < 2; ++i)
#pragma unroll
    for (int j = 0; j < 4; ++j) acc[i][j] = (float4v){0.f, 0.f, 0.f, 0.f};

  auto stage = [&](int buf, int k0) {         // 6 global_load_lds / thread
#pragma unroll
    for (int it = 0; it < 2; ++it) {
      int fw = it * 256 + wid * 64;
      int f = fw + lane;
      int row = f >> 3, c8 = (f & 7) ^ (row & 7);
      load_lds16(gA + (size_t)row * F_ + k0 + c8 * 8, &lA[buf][fw * 8]);
    }
#pragma unroll
    for (int it = 0; it < 4; ++it) {
      int fw = it * 256 + wid * 64;
      int f = fw + lane;
      int row = f >> 3, c8 = (f & 7) ^ (row & 7);
      load_lds16(gB + (size_t)row * F_ + k0 + c8 * 8, &lB[buf][fw * 8]);
    }
  };

  stage(0, 0);

  for (int kt = 0; kt < 8; ++kt) {
    int cur = kt & 1;
    if (kt + 1 < 8) {
      stage(cur ^ 1, (kt + 1) * 64);
      asm volatile("s_waitcnt vmcnt(6)" ::: "memory");
    } else {
      asm volatile("s_waitcnt vmcnt(0)" ::: "memory");
    }
    __builtin_amdgcn_sched_barrier(0);
    barrier_nodrain();
#pragma unroll
    for (int kc = 0; kc < 2; ++kc) {
      short8 af[2], bf[4];
#pragma unroll
      for (int i = 0; i < 2; ++i) {
        int r = wm * 32 + i * 16 + l15;
        af[i] = *(const short8*)&lA[cur][r * 64 + ((kc * 4 + quad) ^ sw) * 8];
      }
#pragma unroll
      for (int j = 0; j < 4; ++j) {
        int n = wn * 64 + j * 16 + l15;
        bf[j] = *(const short8*)&lB[cur][n * 64 + ((kc * 4 + quad) ^ sw) * 8];
      }
#pragma unroll
      for (int i = 0; i < 2; ++i)
#pragma unroll
        for (int j = 0; j < 4; ++j)
          acc[i][j] = __builtin_amdgcn_mfma_f32_16x16x32_bf16(af[i], bf[j], acc[i][j], 0, 0, 0);
    }
    barrier_nodrain();
  }

  int rem = cnt - mt * 64;
#pragma unroll
  for (int i = 0; i < 2; ++i)
#pragma unroll
    for (int r = 0; r < 4; ++r) {
      int row = wm * 32 + i * 16 + quad * 4 + r;
      if (row < rem) {
        float* yp = Ye + (size_t)(rbase + row) * D_ + nt * 128 + wn * 64 + l15;
#pragma unroll
        for (int j = 0; j < 4; ++j) yp[j * 16] = acc[i][j][r];
      }
    }
}

// ---------------- combine: out[t] = w0*Ye[r0] + w1*Ye[r1] --------------------
__global__ void combine_k(const float* __restrict__ Ye, const int* __restrict__ slot_row,
                          const float* __restrict__ row_weight, float* __restrict__ out) {
  int t = blockIdx.x;
  int c = threadIdx.x * 4;
  int r0 = slot_row[2 * t], r1 = slot_row[2 * t + 1];
  float4 acc = {0.f, 0.f, 0.f, 0.f};
  if (r0 >= 0) {
    float w = row_weight[r0];
    float4 y = *(const float4*)(Ye + (size_t)r0 * D_ + c);
    acc.x = w * y.x; acc.y = w * y.y; acc.z = w * y.z; acc.w = w * y.w;
  }
  if (r1 >= 0) {
    float w = row_weight[r1];
    float4 y = *(const float4*)(Ye + (size_t)r1 * D_ + c);
    acc.x += w * y.x; acc.y += w * y.y; acc.z += w * y.z; acc.w += w * y.w;
  }
  *(float4*)(out + (size_t)t * D_ + c) = acc;
}

// ---------------- launch ----------------
extern "C" void kernel_launch(void* const* d_in, const int* in_sizes, int n_in,
                              void* d_out, int out_size, void* d_ws, size_t ws_size,
                              hipStream_t stream) {
  const float* hidden  = (const float*)d_in[0];
  const int*   topkidx = (const int*)d_in[1];
  const float* topkw   = (const float*)d_in[2];
  const float* w_gate  = (const float*)d_in[3];
  const float* w_up    = (const float*)d_in[4];
  const float* w_down  = (const float*)d_in[5];
  float* out = (float*)d_out;

  char* ws = (char*)d_ws;
  unsigned short* WdT = (unsigned short*)(ws + OFF_WDT);
  unsigned short* WgT = (unsigned short*)(ws + OFF_WGT);
  unsigned short* WuT = (unsigned short*)(ws + OFF_WUT);
  unsigned short* Xg  = (unsigned short*)(ws + OFF_XG);
  unsigned short* Hb  = (unsigned short*)(ws + OFF_H);
  float* Ye           = (float*)(ws + OFF_YE);   // aliases WgT/WuT/Xg (dead after gemm1)
  int* meta           = (int*)(ws + OFF_META);
  int* cnt_c     = meta;
  int* off_al    = meta + 16;
  int* row_token = meta + 32;
  float* row_weight = (float*)(meta + 32 + ROWS_MAX);
  int* slot_row  = meta + 32 + 2 * ROWS_MAX;

  prep_k<<<E_ + 6144, 256, 0, stream>>>(topkidx, topkw, w_gate, w_up, w_down,
                                        WgT, WuT, WdT, cnt_c, off_al,
                                        row_token, row_weight, slot_row);
  gather_k<<<ROWS_MAX, 256, 0, stream>>>(hidden, row_token, Xg);

  gemm1_k<<<4096, 256, 0, stream>>>(Xg, WgT, WuT, Hb, cnt_c, off_al);
  gemm2_k<<<4096, 256, 0, stream>>>(Hb, WdT, Ye, cnt_c, off_al);
  combine_k<<<T_, 256, 0, stream>>>(Ye, slot_row, row_weight, out);
}